// Round 6
// baseline (312.874 us; speedup 1.0000x reference)
//
#include <hip/hip_runtime.h>
#include <hip/hip_bf16.h>
#include <math.h>

#define BDIM 4
#define VDIM 8
#define NDIM 256
#define CDIM 768
#define HDIM 12
#define DHE  64
#define C3   (3*CDIM)
#define ROWS (BDIM*VDIM*NDIM)
#define KEYS (VDIM*NDIM)   // 2048

typedef __attribute__((ext_vector_type(8))) short short8;   // 8 bf16 = 4 VGPR
typedef __attribute__((ext_vector_type(4))) float float4v;  // MFMA acc

__device__ inline unsigned short f2bf(float f) {
    unsigned int u = __builtin_bit_cast(unsigned int, f);
    u += 0x7fffu + ((u >> 16) & 1u);   // RNE
    return (unsigned short)(u >> 16);
}

// async global->LDS DMA, 16 B per lane; LDS dest must be linear in lane id
__device__ __forceinline__ void gld_lds16(const unsigned short* g,
                                          unsigned short* l) {
    __builtin_amdgcn_global_load_lds(
        (const __attribute__((address_space(1))) unsigned int*)g,
        (__attribute__((address_space(3))) unsigned int*)l, 16, 0, 0);
}

// ---------------------------------------------------------------------------
// fp32 -> bf16 cast, vectorized (n4 = #float4 groups)
// ---------------------------------------------------------------------------
__global__ void cast_bf16_kernel(const float* __restrict__ src,
                                 unsigned short* __restrict__ dst, int n4) {
    int i = blockIdx.x * blockDim.x + threadIdx.x;
    const int stride = gridDim.x * blockDim.x;
    for (; i < n4; i += stride) {
        float4 f = ((const float4*)src)[i];
        ushort4 o;
        o.x = f2bf(f.x); o.y = f2bf(f.y); o.z = f2bf(f.z); o.w = f2bf(f.w);
        ((ushort4*)dst)[i] = o;
    }
}

// ---------------------------------------------------------------------------
// bf16 MFMA GEMM for QKV proj, now with global_load_lds width-16 staging.
// LDS layout [kc][row][8] unchanged (frag reads identical to round-2);
// staging chunk index c = t + 256*i maps kc = c>>7, r = c&127 so the DMA
// dest is wave-uniform base + lane*16 as required.
// ---------------------------------------------------------------------------
__global__ __launch_bounds__(256) void gemm_qkv_mfma(
    const unsigned short* __restrict__ A,   // [8192][768] bf16
    const unsigned short* __restrict__ W,   // [2304][768] bf16
    const float* __restrict__ bias,
    unsigned short* __restrict__ out)       // [8192][2304] bf16
{
    __shared__ unsigned short As[4][128][8];
    __shared__ unsigned short Ws[4][128][8];
    const int t = threadIdx.x;
    const int wave = t >> 6, lane = t & 63;
    const int m = lane & 15, quad = lane >> 4;
    const int wr = (wave >> 1) * 64, wc = (wave & 1) * 64;
    const int row0 = blockIdx.y * 128, col0 = blockIdx.x * 128;

    float4v acc[4][4] = {};

    for (int k0 = 0; k0 < CDIM; k0 += 32) {
        #pragma unroll
        for (int i = 0; i < 2; i++) {
            const int c = t + 256 * i;
            const int r = c & 127, kc = c >> 7;
            gld_lds16(&A[(size_t)(row0 + r) * CDIM + k0 + kc * 8], &As[kc][r][0]);
            gld_lds16(&W[(size_t)(col0 + r) * CDIM + k0 + kc * 8], &Ws[kc][r][0]);
        }
        __syncthreads();   // drains vmcnt -> DMA visible
        short8 a[4], b[4];
        #pragma unroll
        for (int rt = 0; rt < 4; rt++) a[rt] = *(const short8*)&As[quad][wr + rt * 16 + m][0];
        #pragma unroll
        for (int ct = 0; ct < 4; ct++) b[ct] = *(const short8*)&Ws[quad][wc + ct * 16 + m][0];
        #pragma unroll
        for (int rt = 0; rt < 4; rt++)
            #pragma unroll
            for (int ct = 0; ct < 4; ct++)
                acc[rt][ct] = __builtin_amdgcn_mfma_f32_16x16x32_bf16(
                    a[rt], b[ct], acc[rt][ct], 0, 0, 0);
        __syncthreads();
    }

    #pragma unroll
    for (int ct = 0; ct < 4; ct++) {
        const int col = col0 + wc + ct * 16 + m;
        const float bv = bias[col];
        #pragma unroll
        for (int rt = 0; rt < 4; rt++) {
            const size_t row = (size_t)row0 + wr + rt * 16 + quad * 4;
            #pragma unroll
            for (int r = 0; r < 4; r++)
                out[(row + r) * C3 + col] = f2bf(acc[rt][ct][r] + bv);
        }
    }
}

// ---------------------------------------------------------------------------
// V transpose: qkv v-part [b][key 2048][h][64] -> vT [b][h][64][2048]
// ---------------------------------------------------------------------------
__global__ __launch_bounds__(256) void transpose_v(
    const unsigned short* __restrict__ qkv, unsigned short* __restrict__ vT)
{
    __shared__ unsigned short T[64][72];
    const int kt = blockIdx.x, h = blockIdx.y, b = blockIdx.z;
    const int t = threadIdx.x;
    #pragma unroll
    for (int i = 0; i < 2; i++) {
        const int key = i * 32 + (t >> 3);
        const int dc = t & 7;
        const size_t row = (size_t)(b * KEYS + kt * 64 + key);
        *(uint4*)&T[key][dc * 8] =
            *(const uint4*)&qkv[row * C3 + 2 * CDIM + h * DHE + dc * 8];
    }
    __syncthreads();
    #pragma unroll
    for (int i = 0; i < 2; i++) {
        const int d = i * 32 + (t >> 3);
        const int kg = t & 7;
        unsigned short tmp[8];
        #pragma unroll
        for (int j = 0; j < 8; j++) tmp[j] = T[kg * 8 + j][d];
        *(uint4*)&vT[((size_t)((b * HDIM + h) * DHE + d)) * KEYS + kt * 64 + kg * 8] =
            *(uint4*)tmp;
    }
}

// ---------------------------------------------------------------------------
// MFMA flash attention, round 6 = round-5 inner loops + XCD-grouped swizzle.
// Flat grid 768; assuming XCD = linear_block_id % 8, the 16 blocks sharing
// one (b,h)'s K/V are given ids congruent mod 8 -> same XCD -> K/V fetched
// once per L2 instead of ~8x (6 groups x 512 KB = 3 MB < 4 MB L2).
// ---------------------------------------------------------------------------
__global__ __launch_bounds__(256, 3) void attn_mfma(
    const unsigned short* __restrict__ qkv,  // [8192][2304] bf16
    const unsigned short* __restrict__ vT,   // [4][12][64][2048] bf16
    const int* __restrict__ is_ref,
    unsigned short* __restrict__ ctx)        // [8192][768] bf16
{
    const int gid = blockIdx.x;
    const int xcd = gid & 7;
    const int slot = gid >> 3;               // 0..95
    const int grp = xcd * 6 + (slot >> 4);   // 0..47 = (b,h)
    const int sub = slot & 15;               // 0..15 = (half,v)
    const int b = grp / HDIM, h = grp % HDIM;
    const int v = sub & 7, half = sub >> 3;

    const int t = threadIdx.x, wave = t >> 6, lane = t & 63;
    const int m = lane & 15, quad = lane >> 4;
    const int n0 = half * 128 + wave * 32;

    __shared__ unsigned short Ks[128][64];   // [key][dim], dg' = dg ^ (key&7)
    __shared__ unsigned short Vs[64][128];   // [dim][key], kg' = kg ^ (dim&15)
    __shared__ unsigned short Ps[4][32][72]; // [wave][query][64-key half]

    const int my_ref = is_ref[b * VDIM + v];
    unsigned amask = 0;
    #pragma unroll
    for (int w = 0; w < VDIM; w++)
        if ((is_ref[b * VDIM + w] != 0) ^ (my_ref != 0)) amask |= 1u << w;
    const int nChunks = 2 * __popc(amask);

    const float c1 = 0.18033688f;  // 0.125 * log2(e)

    // Q A-frags: A[m][k=quad*8+j], two 32-dim K-steps
    short8 aq[2][2];
    #pragma unroll
    for (int rt = 0; rt < 2; rt++) {
        const size_t row = (size_t)((b * VDIM + v) * NDIM) + n0 + rt * 16 + m;
        #pragma unroll
        for (int ks = 0; ks < 2; ks++)
            aq[rt][ks] = *(const short8*)&qkv[row * C3 + h * DHE + ks * 32 + quad * 8];
    }

    float rs[2][4] = {};
    float4v O[2][4] = {};

    // staging thread coords
    const int k_key = t >> 3, k_dg = t & 7;    // key = i*32 + k_key
    const int v_dim = t >> 4, v_kg = t & 15;   // dim = i*16 + v_dim

    const unsigned short* vTb = vT + (size_t)(b * HDIM + h) * DHE * KEYS;

    uint4 kreg[4], vreg[4];
    unsigned rem = amask;
    int wcur = __builtin_ffs((int)rem) - 1;

    if (nChunks > 0) {
        const unsigned short* kb =
            qkv + (size_t)((b * VDIM + wcur) * NDIM) * C3 + CDIM + h * DHE;
        #pragma unroll
        for (int i = 0; i < 4; i++)
            kreg[i] = *(const uint4*)&kb[(size_t)(i * 32 + k_key) * C3 + k_dg * 8];
        #pragma unroll
        for (int i = 0; i < 4; i++)
            vreg[i] = *(const uint4*)&vTb[(size_t)(i * 16 + v_dim) * KEYS
                                          + wcur * NDIM + v_kg * 8];
    }

    for (int ci = 0; ci < nChunks; ci++) {
        __syncthreads();   // prev chunk's LDS reads complete
        #pragma unroll
        for (int i = 0; i < 4; i++)
            *(uint4*)&Ks[i * 32 + k_key][(k_dg ^ (k_key & 7)) * 8] = kreg[i];
        #pragma unroll
        for (int i = 0; i < 4; i++)
            *(uint4*)&Vs[i * 16 + v_dim][(v_kg ^ v_dim) * 8] = vreg[i];

        if (ci + 1 < nChunks) {   // prefetch next chunk into regs
            int wn, m0n;
            if ((ci & 1) == 0) { wn = wcur; m0n = 128; }
            else {
                unsigned r2 = rem & (rem - 1);
                wn = __builtin_ffs((int)r2) - 1; m0n = 0;
            }
            const unsigned short* kb =
                qkv + (size_t)((b * VDIM + wn) * NDIM + m0n) * C3 + CDIM + h * DHE;
            #pragma unroll
            for (int i = 0; i < 4; i++)
                kreg[i] = *(const uint4*)&kb[(size_t)(i * 32 + k_key) * C3 + k_dg * 8];
            #pragma unroll
            for (int i = 0; i < 4; i++)
                vreg[i] = *(const uint4*)&vTb[(size_t)(i * 16 + v_dim) * KEYS
                                              + wn * NDIM + m0n + v_kg * 8];
        }
        __syncthreads();   // LDS tiles visible

        // two 64-key halves: S-tiles -> Ps, then PV for that half
        #pragma unroll
        for (int hk = 0; hk < 2; hk++) {
            #pragma unroll
            for (int nt4 = 0; nt4 < 4; nt4++) {
                const int nt = hk * 4 + nt4;
                const short8 bk0 = *(const short8*)&Ks[nt * 16 + m][(quad ^ (m & 7)) * 8];
                const short8 bk1 = *(const short8*)&Ks[nt * 16 + m][((4 + quad) ^ (m & 7)) * 8];
                #pragma unroll
                for (int rt = 0; rt < 2; rt++) {
                    float4v s = {};
                    s = __builtin_amdgcn_mfma_f32_16x16x32_bf16(aq[rt][0], bk0, s, 0, 0, 0);
                    s = __builtin_amdgcn_mfma_f32_16x16x32_bf16(aq[rt][1], bk1, s, 0, 0, 0);
                    #pragma unroll
                    for (int r = 0; r < 4; r++) {
                        const float p = __builtin_amdgcn_exp2f(s[r] * c1);
                        rs[rt][r] += p;
                        Ps[wave][rt * 16 + quad * 4 + r][nt4 * 16 + m] = f2bf(p);
                    }
                }
            }
            #pragma unroll
            for (int kk = 0; kk < 2; kk++) {
                const short8 ap0 = *(const short8*)&Ps[wave][m][kk * 32 + quad * 8];
                const short8 ap1 = *(const short8*)&Ps[wave][16 + m][kk * 32 + quad * 8];
                #pragma unroll
                for (int ct = 0; ct < 4; ct++) {
                    const short8 bv = *(const short8*)&Vs[ct * 16 + m]
                        [((hk * 8 + kk * 4 + quad) ^ m) * 8];
                    O[0][ct] = __builtin_amdgcn_mfma_f32_16x16x32_bf16(ap0, bv, O[0][ct], 0, 0, 0);
                    O[1][ct] = __builtin_amdgcn_mfma_f32_16x16x32_bf16(ap1, bv, O[1][ct], 0, 0, 0);
                }
            }
        }
        if (ci & 1) { rem &= rem - 1; wcur = __builtin_ffs((int)rem) - 1; }
    }

    // final: reduce l over the 16 m-lanes, normalize, write
    #pragma unroll
    for (int rt = 0; rt < 2; rt++) {
        float inv[4];
        #pragma unroll
        for (int r = 0; r < 4; r++) {
            float x = rs[rt][r];
            #pragma unroll
            for (int off = 1; off < 16; off <<= 1)
                x += __shfl_xor(x, off, 64);
            inv[r] = (x > 0.f) ? 1.f / x : 0.f;
        }
        const size_t rowg = (size_t)((b * VDIM + v) * NDIM) + n0 + rt * 16 + quad * 4;
        #pragma unroll
        for (int ct = 0; ct < 4; ct++)
            #pragma unroll
            for (int r = 0; r < 4; r++)
                ctx[(rowg + r) * CDIM + h * DHE + ct * 16 + m] = f2bf(O[rt][ct][r] * inv[r]);
    }
}

// ---------------------------------------------------------------------------
// bf16 MFMA GEMM for out-proj, global_load_lds staging (same layout trick).
// ---------------------------------------------------------------------------
__global__ __launch_bounds__(256) void gemm_out_mfma(
    const unsigned short* __restrict__ A,   // ctx_b [8192][768]
    const unsigned short* __restrict__ W,   // wout_b [768][768]
    const float* __restrict__ bias,
    const float* __restrict__ feats,
    const int* __restrict__ is_ref,
    float* __restrict__ out)                // [8192][768] fp32
{
    __shared__ unsigned short As[4][128][8];
    __shared__ unsigned short Ws[4][128][8];
    const int t = threadIdx.x;
    const int wave = t >> 6, lane = t & 63;
    const int m = lane & 15, quad = lane >> 4;
    const int wr = (wave >> 1) * 64, wc = (wave & 1) * 64;
    const int row0 = blockIdx.y * 128, col0 = blockIdx.x * 128;

    float4v acc[4][4] = {};

    for (int k0 = 0; k0 < CDIM; k0 += 32) {
        #pragma unroll
        for (int i = 0; i < 2; i++) {
            const int c = t + 256 * i;
            const int r = c & 127, kc = c >> 7;
            gld_lds16(&A[(size_t)(row0 + r) * CDIM + k0 + kc * 8], &As[kc][r][0]);
            gld_lds16(&W[(size_t)(col0 + r) * CDIM + k0 + kc * 8], &Ws[kc][r][0]);
        }
        __syncthreads();
        short8 a[4], b[4];
        #pragma unroll
        for (int rt = 0; rt < 4; rt++) a[rt] = *(const short8*)&As[quad][wr + rt * 16 + m][0];
        #pragma unroll
        for (int ct = 0; ct < 4; ct++) b[ct] = *(const short8*)&Ws[quad][wc + ct * 16 + m][0];
        #pragma unroll
        for (int rt = 0; rt < 4; rt++)
            #pragma unroll
            for (int ct = 0; ct < 4; ct++)
                acc[rt][ct] = __builtin_amdgcn_mfma_f32_16x16x32_bf16(
                    a[rt], b[ct], acc[rt][ct], 0, 0, 0);
        __syncthreads();
    }

    const int bidx = row0 / (VDIM * NDIM);
    const int vidx = (row0 / NDIM) % VDIM;
    const int my = is_ref[bidx * VDIM + vidx];
    bool has = false;
    #pragma unroll
    for (int w = 0; w < VDIM; w++) has = has || (is_ref[bidx * VDIM + w] != my);

    #pragma unroll
    for (int ct = 0; ct < 4; ct++) {
        const int col = col0 + wc + ct * 16 + m;
        const float bv = bias[col];
        #pragma unroll
        for (int rt = 0; rt < 4; rt++) {
            const size_t row = (size_t)row0 + wr + rt * 16 + quad * 4;
            #pragma unroll
            for (int r = 0; r < 4; r++) {
                float o = acc[rt][ct][r] + bv;
                if (!has) o = feats[(row + r) * CDIM + col];
                out[(row + r) * CDIM + col] = o;
            }
        }
    }
}

extern "C" void kernel_launch(void* const* d_in, const int* in_sizes, int n_in,
                              void* d_out, int out_size, void* d_ws, size_t ws_size,
                              hipStream_t stream) {
    const float* feats = (const float*)d_in[0];
    const int*   is_ref = (const int*)d_in[1];
    const float* w_qkv = (const float*)d_in[2];
    const float* b_qkv = (const float*)d_in[3];
    const float* w_out = (const float*)d_in[4];
    const float* b_out = (const float*)d_in[5];
    float* out = (float*)d_out;

    unsigned short* feats_b = (unsigned short*)d_ws;            // 8192x768
    unsigned short* wqkv_b  = feats_b + (size_t)ROWS * CDIM;    // 2304x768
    unsigned short* wout_b  = wqkv_b + (size_t)C3 * CDIM;       // 768x768
    unsigned short* qkv_b   = wout_b + (size_t)CDIM * CDIM;     // 8192x2304
    unsigned short* vT      = qkv_b + (size_t)ROWS * C3;        // 4x12x64x2048
    unsigned short* ctx_b   = vT + (size_t)BDIM * HDIM * DHE * KEYS; // 8192x768

    cast_bf16_kernel<<<2048, 256, 0, stream>>>(feats, feats_b, ROWS * CDIM / 4);
    cast_bf16_kernel<<<1024, 256, 0, stream>>>(w_qkv, wqkv_b, C3 * CDIM / 4);
    cast_bf16_kernel<<<144, 256, 0, stream>>>(w_out, wout_b, CDIM * CDIM / 4);

    dim3 g1(C3 / 128, ROWS / 128);                              // 18 x 64
    gemm_qkv_mfma<<<g1, 256, 0, stream>>>(feats_b, wqkv_b, b_qkv, qkv_b);

    dim3 gt(KEYS / 64, HDIM, BDIM);                             // 32 x 12 x 4
    transpose_v<<<gt, 256, 0, stream>>>(qkv_b, vT);

    attn_mfma<<<dim3(768), 256, 0, stream>>>(qkv_b, vT, is_ref, ctx_b);

    dim3 g3(CDIM / 128, ROWS / 128);                            // 6 x 64
    gemm_out_mfma<<<g3, 256, 0, stream>>>(ctx_b, wout_b, b_out, feats, is_ref, out);
    (void)in_sizes; (void)n_in; (void)out_size; (void)ws_size;
}